// Round 5
// baseline (177.143 us; speedup 1.0000x reference)
//
#include <hip/hip_runtime.h>
#include <hip/hip_bf16.h>
#include <cmath>

#define BB 4
#define NN 2048
#define DIN 128
#define HH 4
#define HD 32
#define KSEL 204            // int(0.1 * 2048)
#define BH (BB*HH)
#define KPAD 256            // K padded to 8 MFMA steps of 32
#define RPB 8               // rows per coef block

typedef __attribute__((ext_vector_type(8))) short short8;
typedef __attribute__((ext_vector_type(4))) short short4v;
typedef __attribute__((ext_vector_type(4))) float float4v;

static __device__ inline short f2bf(float x) {
    __hip_bfloat16 b = __float2bfloat16(x);   // RNE
    return __builtin_bit_cast(short, b);
}

// ---------------------------------------------------------------------------
// K1: fused: (hh==0 blocks) h->bf16 convert; (all) s_i/s_j f32-exact dots.
// grid BH*8; block = (bh, 256 rows). Also zeroes rank.
__global__ __launch_bounds__(256) void hs_kernel(const float* __restrict__ h,
                                                 const float* __restrict__ W,
                                                 const float* __restrict__ a,
                                                 short* __restrict__ hbf,
                                                 float* __restrict__ si, float* __restrict__ sj,
                                                 int* __restrict__ rank) {
    int bh = blockIdx.x >> 3, chunk = blockIdx.x & 7;
    int b = bh >> 2, hh = bh & 3;
    int t = threadIdx.x;
    // head-0 blocks: coalesced convert of this 256-row range (also warms L2)
    if (hh == 0) {
        size_t base4 = ((size_t)b * NN + chunk * 256) * (DIN / 4);
        const float4* src = (const float4*)h + base4;
        short4v* dst = (short4v*)hbf + base4;
        for (int e = t; e < 256 * (DIN / 4); e += 256) {
            float4 x = src[e];
            short4v r;
            r[0] = f2bf(x.x); r[1] = f2bf(x.y); r[2] = f2bf(x.z); r[3] = f2bf(x.w);
            dst[e] = r;
        }
    }
    __shared__ float w1[128], w2[128];
    {   // wa = W[hh] @ a-halves, computed in-block
        int f = t & 127, half = t >> 7;
        const float* Wp = W + (size_t)hh * (DIN * HD) + f * HD;
        const float* ap = a + hh * 64 + half * 32;
        float acc = 0.f;
#pragma unroll
        for (int d = 0; d < 32; ++d) acc += Wp[d] * ap[d];
        if (half == 0) w1[f] = acc; else w2[f] = acc;
    }
    __syncthreads();
    int n = chunk * 256 + t;
    const float4* hr = (const float4*)(h + ((size_t)b * NN + n) * DIN);
    float s1 = 0.f, s2 = 0.f;
#pragma unroll 8
    for (int q = 0; q < 32; ++q) {
        float4 x = hr[q];
        s1 += x.x * w1[q*4] + x.y * w1[q*4+1] + x.z * w1[q*4+2] + x.w * w1[q*4+3];
        s2 += x.x * w2[q*4] + x.y * w2[q*4+1] + x.z * w2[q*4+2] + x.w * w2[q*4+3];
    }
    int o = bh * NN + n;
    si[o] = s1; sj[o] = s2; rank[o] = 0;
}

// ---------------------------------------------------------------------------
// K2: Whg[bh][n][d] (bf16) = hbf[b][n][:] @ W[h][:][d]  via MFMA 16x16x32 bf16
__global__ __launch_bounds__(256) void wh_kernel(const short* __restrict__ hbf,
                                                 const float* __restrict__ W,
                                                 short* __restrict__ Whg) {
    int bh = blockIdx.x >> 4, rtile = blockIdx.x & 15;
    int b = bh >> 2, hh = bh & 3;
    __shared__ short WT[32][136];   // WT[n][k] = bf16(W[hh][k][n])
    int t = threadIdx.x;
    for (int e = t; e < 32 * 128; e += 256) {
        int n = e >> 7, k = e & 127;
        WT[n][k] = f2bf(W[(size_t)hh * (DIN * HD) + k * HD + n]);
    }
    __syncthreads();
    int w = t >> 6, lane = t & 63, mr = lane & 15, quad = lane >> 4;
    int row_base = rtile * 128;
#pragma unroll
    for (int q = 0; q < 4; ++q) {
        int tt = w * 4 + q;
        int rt = tt >> 1, ct = tt & 1;
        int row0 = row_base + rt * 16;
        const short* hrow = hbf + ((size_t)b * NN + row0 + mr) * DIN + quad * 8;
        float4v acc = {0.f, 0.f, 0.f, 0.f};
#pragma unroll
        for (int ks = 0; ks < 4; ++ks) {
            short8 afr = *(const short8*)(hrow + ks * 32);
            short8 bfr = *(const short8*)&WT[ct * 16 + mr][ks * 32 + quad * 8];
            acc = __builtin_amdgcn_mfma_f32_16x16x32_bf16(afr, bfr, acc, 0, 0, 0);
        }
#pragma unroll
        for (int r = 0; r < 4; ++r) {
            int rowg = row0 + quad * 4 + r;
            Whg[((size_t)bh * NN + rowg) * HD + ct * 16 + mr] = f2bf(acc[r]);
        }
    }
}

// ---------------------------------------------------------------------------
// K3: partial rank counts. grid = BH*16; block handles 128 jp's vs all 2048 j's.
__global__ __launch_bounds__(256) void rankp_kernel(const float* __restrict__ sj,
                                                    int* __restrict__ rank) {
    int bh = blockIdx.x >> 4, jpc = blockIdx.x & 15;
    __shared__ float sv[128];
    int t = threadIdx.x;
    if (t < 128) sv[t] = sj[bh * NN + jpc * 128 + t];
    __syncthreads();
    int j0 = t * 8;
    const float* sjb = sj + bh * NN;
    float v[8]; int cnt[8];
#pragma unroll
    for (int r = 0; r < 8; ++r) { v[r] = sjb[j0 + r]; cnt[r] = 0; }
    int jpbase = jpc * 128;
    for (int jp = 0; jp < 128; ++jp) {
        float x = sv[jp];
        int jg = jpbase + jp;
#pragma unroll
        for (int r = 0; r < 8; ++r)
            cnt[r] += (x > v[r]) ? 1 : ((x == v[r] && jg < j0 + r) ? 1 : 0);
    }
#pragma unroll
    for (int r = 0; r < 8; ++r) atomicAdd(&rank[bh * NN + j0 + r], cnt[r]);
}

// ---------------------------------------------------------------------------
// K4: compact selected (rank < KSEL) ascending; sjsel + max; ALSO stage
// Whsel[bh][d][jj] bf16 (zero-padded K to 256) for pv B-fragments.
__global__ __launch_bounds__(256) void compact_kernel(const float* __restrict__ sj,
                                                      const int* __restrict__ rank,
                                                      const short* __restrict__ Whg,
                                                      int* __restrict__ idxsel,
                                                      float* __restrict__ sjsel,
                                                      float* __restrict__ sjmax,
                                                      short* __restrict__ Whsel) {
    int bh = blockIdx.x;
    int t = threadIdx.x, lane = t & 63, w = t >> 6;
    const int base = bh * NN;
    __shared__ int idxLDS[KSEL];
    int flags[8], cnt = 0;
    float lmax = -1e30f;
    int j0 = t * 8;
#pragma unroll
    for (int r = 0; r < 8; ++r) {
        int j = j0 + r;
        int f = (rank[base + j] < KSEL) ? 1 : 0;
        flags[r] = f; cnt += f;
        lmax = fmaxf(lmax, sj[base + j]);
    }
    int sc = cnt;
#pragma unroll
    for (int off = 1; off < 64; off <<= 1) {
        int u = __shfl_up(sc, off);
        if (lane >= off) sc += u;
    }
    float mx = lmax;
#pragma unroll
    for (int off = 32; off >= 1; off >>= 1) mx = fmaxf(mx, __shfl_xor(mx, off));
    __shared__ int wtot[4], woff[4];
    __shared__ float wmax[4];
    if (lane == 63) wtot[w] = sc;
    if (lane == 0) wmax[w] = mx;
    __syncthreads();
    if (t == 0) {
        int run = 0;
        for (int i = 0; i < 4; ++i) { woff[i] = run; run += wtot[i]; }
        sjmax[bh] = fmaxf(fmaxf(wmax[0], wmax[1]), fmaxf(wmax[2], wmax[3]));
    }
    __syncthreads();
    int pos = woff[w] + sc - cnt;
#pragma unroll
    for (int r = 0; r < 8; ++r) {
        if (flags[r]) {
            int j = j0 + r;
            idxsel[bh * KSEL + pos] = j;
            sjsel[bh * KSEL + pos] = sj[base + j];
            idxLDS[pos] = j;
            pos++;
        }
    }
    __syncthreads();
    // Whsel[bh][d][jj]: B-operand layout, contiguous jj, zero K-tail
    for (int e = t; e < HD * KPAD; e += 256) {
        int d = e >> 8, jj = e & 255;
        short v = 0;
        if (jj < KSEL) v = Whg[((size_t)bh * NN + idxLDS[jj]) * HD + d];
        Whsel[((size_t)bh * HD + d) * KPAD + jj] = v;
    }
}

// ---------------------------------------------------------------------------
// K5a: coefficients. Block = (b, RPB rows, 4 heads-as-waves). adj rows loaded
// DENSE into double-buffered LDS, shared by all 4 heads. PS = exp*adj (bf16,
// NO 1/z — folded into pv); invZ written per (bh,row). ~23 KB LDS.
__global__ __launch_bounds__(256) void coef_kernel(
        const float* __restrict__ adj, const float* __restrict__ si,
        const int* __restrict__ idxsel, const float* __restrict__ sjsel,
        const float* __restrict__ sjmax, short* __restrict__ PS,
        float* __restrict__ invZ) {
    int b = blockIdx.x >> 8;          // 4
    int chunk = blockIdx.x & 255;     // 256 chunks of RPB=8 rows
    __shared__ float adjbuf[2][NN];
    __shared__ int   idxS[HH][KSEL];
    __shared__ float sjS[HH][KSEL];
    __shared__ float smaxS[HH];
    int t = threadIdx.x, w = t >> 6, lane = t & 63;
    for (int e = t; e < HH * KSEL; e += 256) {
        int hh = e / KSEL, jj = e - hh * KSEL;
        idxS[hh][jj] = idxsel[(b * HH + hh) * KSEL + jj];
        sjS[hh][jj]  = sjsel[(b * HH + hh) * KSEL + jj];
    }
    if (t < HH) smaxS[t] = sjmax[b * HH + t];
    int i0 = chunk * RPB;
    const float* adjb = adj + (size_t)b * NN * NN;
    // stage row 0
    {
        const float4* src = (const float4*)(adjb + (size_t)i0 * NN);
        ((float4*)adjbuf[0])[t]       = src[t];
        ((float4*)adjbuf[0])[t + 256] = src[t + 256];
    }
    __syncthreads();
    int bh = b * HH + w;
    float smax = smaxS[w];
    for (int r = 0; r < RPB; ++r) {
        // prefetch next row into registers (no LDS write yet)
        float4 p0, p1;
        if (r + 1 < RPB) {
            const float4* src = (const float4*)(adjb + (size_t)(i0 + r + 1) * NN);
            p0 = src[t]; p1 = src[t + 256];
        }
        const float* ab = adjbuf[r & 1];
        int i = i0 + r;
        float siv = si[(size_t)bh * NN + i];
        float m = siv + smax;
        m = (m >= 0.f) ? m : 0.2f * m;
        float z = 0.f;
        short* prow = PS + ((size_t)bh * NN + i) * KPAD;
#pragma unroll
        for (int k = 0; k < 4; ++k) {
            int jj = k * 64 + lane;
            bool valid = jj < KSEL;
            int j = valid ? idxS[w][jj] : 0;
            float av = ab[j];
            float e = siv + (valid ? sjS[w][jj] : 0.f);
            e = (e >= 0.f) ? e : 0.2f * e;
            float c = valid ? __expf(e - m) : 0.f;
            z += c;
            prow[jj] = f2bf(c * av);    // store immediately; z-reduce later
        }
#pragma unroll
        for (int off = 32; off >= 1; off >>= 1) z += __shfl_xor(z, off);
        if (lane == 0) invZ[(size_t)bh * NN + i] = 1.0f / z;
        // write prefetched row AFTER compute, then barrier
        if (r + 1 < RPB) {
            float4* dst = (float4*)adjbuf[(r + 1) & 1];
            dst[t] = p0; dst[t + 256] = p1;
        }
        __syncthreads();
    }
}

// ---------------------------------------------------------------------------
// K5b: out = (P @ Whsel) * invZ via MFMA. No LDS; fragments from global.
__global__ __launch_bounds__(256) void pv_kernel(
        const short* __restrict__ PS, const short* __restrict__ Whsel,
        const float* __restrict__ invZ, float* __restrict__ out) {
    int bh = blockIdx.x >> 6, tile = blockIdx.x & 63;
    int b = bh >> 2, hh = bh & 3;
    int t = threadIdx.x, w = t >> 6, lane = t & 63;
    int mr = lane & 15, quad = lane >> 4;
    int mi = w >> 1, ni = w & 1;
    int i0 = tile * 32;
    const short* pA = PS + ((size_t)bh * NN + i0 + mi * 16 + mr) * KPAD + quad * 8;
    const short* pB = Whsel + ((size_t)bh * HD + ni * 16 + mr) * KPAD + quad * 8;
    float4v acc = {0.f, 0.f, 0.f, 0.f};
#pragma unroll
    for (int ks = 0; ks < 8; ++ks) {
        short8 afr = *(const short8*)(pA + ks * 32);
        short8 bfr = *(const short8*)(pB + ks * 32);
        acc = __builtin_amdgcn_mfma_f32_16x16x32_bf16(afr, bfr, acc, 0, 0, 0);
    }
#pragma unroll
    for (int r = 0; r < 4; ++r) {
        int i = i0 + mi * 16 + quad * 4 + r;
        int d = ni * 16 + mr;
        out[((size_t)(b * NN + i)) * (HH * HD) + hh * HD + d] =
            acc[r] * invZ[(size_t)bh * NN + i];
    }
}

// ---------------------------------------------------------------------------
extern "C" void kernel_launch(void* const* d_in, const int* in_sizes, int n_in,
                              void* d_out, int out_size, void* d_ws, size_t ws_size,
                              hipStream_t stream) {
    const float* h   = (const float*)d_in[0];   // [B,N,DIN]
    const float* adj = (const float*)d_in[1];   // [B,N,N]
    const float* W   = (const float*)d_in[2];   // [H,DIN,HD]
    const float* a   = (const float*)d_in[3];   // [H,2*HD]
    float* out = (float*)d_out;                 // [B,N,H*HD]

    float* si     = (float*)d_ws;                        // BH*NN f32
    float* sj     = si + (size_t)BH * NN;                // BH*NN
    float* invZ   = sj + (size_t)BH * NN;                // BH*NN
    float* sjsel  = invZ + (size_t)BH * NN;              // BH*KSEL
    float* sjmax  = sjsel + (size_t)BH * KSEL;           // BH (pad 16)
    int*   idxsel = (int*)(sjmax + 16);                  // BH*KSEL
    int*   rank   = idxsel + (size_t)BH * KSEL;          // BH*NN
    short* hbf    = (short*)(rank + (size_t)BH * NN);    // BB*NN*DIN bf16
    short* Whg    = hbf + (size_t)BB * NN * DIN;         // BH*NN*HD bf16
    short* Whsel  = Whg + (size_t)BH * NN * HD;          // BH*HD*KPAD bf16
    short* PS     = Whsel + (size_t)BH * HD * KPAD;      // BH*NN*KPAD bf16

    hs_kernel<<<BH * 8, 256, 0, stream>>>(h, W, a, hbf, si, sj, rank);
    wh_kernel<<<BH * 16, 256, 0, stream>>>(hbf, W, Whg);
    rankp_kernel<<<BH * 16, 256, 0, stream>>>(sj, rank);
    compact_kernel<<<BH, 256, 0, stream>>>(sj, rank, Whg, idxsel, sjsel, sjmax, Whsel);
    coef_kernel<<<BB * (NN / RPB), 256, 0, stream>>>(adj, si, idxsel, sjsel, sjmax, PS, invZ);
    pv_kernel<<<BH * 64, 256, 0, stream>>>(PS, Whsel, invZ, out);
}

// Round 6
// 171.668 us; speedup vs baseline: 1.0319x; 1.0319x over previous
//
#include <hip/hip_runtime.h>
#include <hip/hip_bf16.h>
#include <cmath>

#define BB 4
#define NN 2048
#define DIN 128
#define HH 4
#define HD 32
#define KSEL 204            // int(0.1 * 2048)
#define BH (BB*HH)
#define KPAD 256            // K padded to 8 MFMA steps of 32
#define CRPB 4              // rows per coef block (all resident in LDS)

typedef __attribute__((ext_vector_type(8))) short short8;
typedef __attribute__((ext_vector_type(4))) short short4v;
typedef __attribute__((ext_vector_type(4))) float float4v;

static __device__ inline short f2bf(float x) {
    __hip_bfloat16 b = __float2bfloat16(x);   // RNE
    return __builtin_bit_cast(short, b);
}

// ---------------------------------------------------------------------------
// K0: h (f32) -> hbf (bf16), coalesced. 1M elems, 4 per thread.
__global__ __launch_bounds__(256) void hcvt_kernel(const float* __restrict__ h,
                                                   short* __restrict__ hbf) {
    int tid = blockIdx.x * 256 + threadIdx.x;
    float4 x = ((const float4*)h)[tid];
    short4v r;
    r[0] = f2bf(x.x); r[1] = f2bf(x.y); r[2] = f2bf(x.z); r[3] = f2bf(x.w);
    *(short4v*)(hbf + (size_t)tid * 4) = r;
}

// ---------------------------------------------------------------------------
// K1: s_i = h.(W@a1), s_j = h.(W@a2)  (all-f32 exact; feeds top-k).
__global__ __launch_bounds__(256) void s_kernel(const float* __restrict__ h,
                                                const float* __restrict__ W,
                                                const float* __restrict__ a,
                                                float* __restrict__ si, float* __restrict__ sj) {
    int bh = blockIdx.x >> 3, chunk = blockIdx.x & 7;
    int b = bh >> 2, hh = bh & 3;
    __shared__ float w1[128], w2[128];
    int t = threadIdx.x;
    {   // wa = W[hh] @ a-halves, computed in-block
        int f = t & 127, half = t >> 7;
        const float* Wp = W + (size_t)hh * (DIN * HD) + f * HD;
        const float* ap = a + hh * 64 + half * 32;
        float acc = 0.f;
#pragma unroll
        for (int d = 0; d < 32; ++d) acc += Wp[d] * ap[d];
        if (half == 0) w1[f] = acc; else w2[f] = acc;
    }
    __syncthreads();
    int n = chunk * 256 + t;
    const float4* hr = (const float4*)(h + ((size_t)b * NN + n) * DIN);
    float s1 = 0.f, s2 = 0.f;
#pragma unroll 8
    for (int q = 0; q < 32; ++q) {
        float4 x = hr[q];
        s1 += x.x * w1[q*4] + x.y * w1[q*4+1] + x.z * w1[q*4+2] + x.w * w1[q*4+3];
        s2 += x.x * w2[q*4] + x.y * w2[q*4+1] + x.z * w2[q*4+2] + x.w * w2[q*4+3];
    }
    int o = bh * NN + n;
    si[o] = s1; sj[o] = s2;
}

// ---------------------------------------------------------------------------
// K2: Whg[bh][n][d] (bf16) = hbf[b][n][:] @ W[h][:][d]  via MFMA 16x16x32 bf16
__global__ __launch_bounds__(256) void wh_kernel(const short* __restrict__ hbf,
                                                 const float* __restrict__ W,
                                                 short* __restrict__ Whg) {
    int bh = blockIdx.x >> 4, rtile = blockIdx.x & 15;
    int b = bh >> 2, hh = bh & 3;
    __shared__ short WT[32][136];   // WT[n][k] = bf16(W[hh][k][n])
    int t = threadIdx.x;
    for (int e = t; e < 32 * 128; e += 256) {
        int n = e >> 7, k = e & 127;
        WT[n][k] = f2bf(W[(size_t)hh * (DIN * HD) + k * HD + n]);
    }
    __syncthreads();
    int w = t >> 6, lane = t & 63, mr = lane & 15, quad = lane >> 4;
    int row_base = rtile * 128;
#pragma unroll
    for (int q = 0; q < 4; ++q) {
        int tt = w * 4 + q;
        int rt = tt >> 1, ct = tt & 1;
        int row0 = row_base + rt * 16;
        const short* hrow = hbf + ((size_t)b * NN + row0 + mr) * DIN + quad * 8;
        float4v acc = {0.f, 0.f, 0.f, 0.f};
#pragma unroll
        for (int ks = 0; ks < 4; ++ks) {
            short8 afr = *(const short8*)(hrow + ks * 32);
            short8 bfr = *(const short8*)&WT[ct * 16 + mr][ks * 32 + quad * 8];
            acc = __builtin_amdgcn_mfma_f32_16x16x32_bf16(afr, bfr, acc, 0, 0, 0);
        }
#pragma unroll
        for (int r = 0; r < 4; ++r) {
            int rowg = row0 + quad * 4 + r;
            Whg[((size_t)bh * NN + rowg) * HD + ct * 16 + mr] = f2bf(acc[r]);
        }
    }
}

// ---------------------------------------------------------------------------
// K3: radix-select top-KSEL per (b,h) + compaction + Whsel staging.
// 4-pass byte histogram on sortable keys finds exact threshold key T;
// select key>T plus first (KSEL - n_gt) ties by index (== rank<KSEL semantics).
__global__ __launch_bounds__(256) void select_kernel(
        const float* __restrict__ sj, const short* __restrict__ Whg,
        int* __restrict__ idxsel, float* __restrict__ sjsel,
        float* __restrict__ sjmax, short* __restrict__ Whsel) {
    int bh = blockIdx.x;
    int t = threadIdx.x, lane = t & 63, w = t >> 6;
    __shared__ float sv[NN];
    __shared__ unsigned kv[NN];
    __shared__ int hist[256];
    __shared__ int binInfo[2];               // [0]=Bsel, [1]=cum_before
    __shared__ int wtotg[4], wtote[4], woffg[4], woffe[4];
    __shared__ float wmax[4];
    __shared__ int idxLDS[KSEL];

    const float* s = sj + (size_t)bh * NN;
    float lmax = -1e30f;
    for (int e = t; e < NN; e += 256) {
        float x = s[e];
        sv[e] = x;
        unsigned u = __builtin_bit_cast(unsigned, x);
        kv[e] = (u & 0x80000000u) ? ~u : (u | 0x80000000u);
        lmax = fmaxf(lmax, x);
    }
#pragma unroll
    for (int off = 32; off >= 1; off >>= 1) lmax = fmaxf(lmax, __shfl_xor(lmax, off));
    if (lane == 0) wmax[w] = lmax;
    __syncthreads();
    if (t == 0) sjmax[bh] = fmaxf(fmaxf(wmax[0], wmax[1]), fmaxf(wmax[2], wmax[3]));

    unsigned prefix = 0;
    int need = KSEL;
    for (int shift = 24; shift >= 0; shift -= 8) {
        hist[t] = 0;
        __syncthreads();
        unsigned hmask = (shift < 24) ? (0xFFFFFFFFu << (shift + 8)) : 0u;
        for (int e = t; e < NN; e += 256) {
            unsigned k = kv[e];
            if (((k ^ prefix) & hmask) == 0)
                atomicAdd(&hist[(k >> shift) & 255], 1);
        }
        __syncthreads();
        if (t == 0) {
            int cum = 0, Bsel = 0;
            for (int bb = 255; bb >= 0; --bb) {
                int hc = hist[bb];
                if (cum + hc >= need) { Bsel = bb; break; }
                cum += hc;
            }
            binInfo[0] = Bsel; binInfo[1] = cum;
        }
        __syncthreads();
        prefix |= ((unsigned)binInfo[0]) << shift;
        need -= binInfo[1];
    }
    unsigned T = prefix;
    int n_gt = KSEL - need;        // count of keys strictly > T

    // ordered compaction: thread t owns indices [t*8, t*8+8)
    int j0 = t * 8;
    unsigned kk[8];
    int cg = 0, ce = 0;
#pragma unroll
    for (int r = 0; r < 8; ++r) {
        kk[r] = kv[j0 + r];
        cg += (kk[r] > T) ? 1 : 0;
        ce += (kk[r] == T) ? 1 : 0;
    }
    int sg = cg, se = ce;
#pragma unroll
    for (int off = 1; off < 64; off <<= 1) {
        int ug = __shfl_up(sg, off), ue = __shfl_up(se, off);
        if (lane >= off) { sg += ug; se += ue; }
    }
    if (lane == 63) { wtotg[w] = sg; wtote[w] = se; }
    __syncthreads();
    if (t == 0) {
        int rg = 0, re = 0;
        for (int i = 0; i < 4; ++i) {
            woffg[i] = rg; rg += wtotg[i];
            woffe[i] = re; re += wtote[i];
        }
    }
    __syncthreads();
    int pg = woffg[w] + sg - cg;   // exclusive prefix among key>T
    int te = woffe[w] + se - ce;   // exclusive prefix among key==T
#pragma unroll
    for (int r = 0; r < 8; ++r) {
        int j = j0 + r;
        if (kk[r] > T) {
            idxsel[bh * KSEL + pg] = j;
            sjsel[bh * KSEL + pg] = sv[j];
            idxLDS[pg] = j;
            pg++;
        } else if (kk[r] == T) {
            if (te < need) {
                int pos = n_gt + te;
                idxsel[bh * KSEL + pos] = j;
                sjsel[bh * KSEL + pos] = sv[j];
                idxLDS[pos] = j;
            }
            te++;
        }
    }
    __syncthreads();
    // Whsel[bh][d][jj]: B-operand layout, contiguous jj, zero K-tail
    for (int e = t; e < HD * KPAD; e += 256) {
        int d = e >> 8, jj = e & 255;
        short v = 0;
        if (jj < KSEL) v = Whg[((size_t)bh * NN + idxLDS[jj]) * HD + d];
        Whsel[((size_t)bh * HD + d) * KPAD + jj] = v;
    }
}

// ---------------------------------------------------------------------------
// K4: coefficients. Block = (b, CRPB rows, 4 heads-as-waves). All CRPB adj
// rows resident in LDS -> ONE barrier; each wave then runs free.
// PS = exp*adj (bf16, no 1/z); invZ written per (bh,row). ~39 KB LDS.
__global__ __launch_bounds__(256) void coef_kernel(
        const float* __restrict__ adj, const float* __restrict__ si,
        const int* __restrict__ idxsel, const float* __restrict__ sjsel,
        const float* __restrict__ sjmax, short* __restrict__ PS,
        float* __restrict__ invZ) {
    int b = blockIdx.x >> 9;          // 4
    int chunk = blockIdx.x & 511;     // 512 chunks of CRPB=4 rows
    __shared__ float adjbuf[CRPB][NN];
    __shared__ int   idxS[HH][KSEL];
    __shared__ float sjS[HH][KSEL];
    __shared__ float smaxS[HH];
    int t = threadIdx.x, w = t >> 6, lane = t & 63;
    int i0 = chunk * CRPB;
    const float* adjb = adj + (size_t)b * NN * NN;
    // stage all 4 rows (coalesced float4) + tables, one barrier
    {
        const float4* src = (const float4*)(adjb + (size_t)i0 * NN);
        float4* dst = (float4*)adjbuf;
#pragma unroll
        for (int q = 0; q < CRPB * 2; ++q)
            dst[q * 256 + t] = src[q * 256 + t];
    }
    for (int e = t; e < HH * KSEL; e += 256) {
        int hh = e / KSEL, jj = e - hh * KSEL;
        idxS[hh][jj] = idxsel[(b * HH + hh) * KSEL + jj];
        sjS[hh][jj]  = sjsel[(b * HH + hh) * KSEL + jj];
    }
    if (t < HH) smaxS[t] = sjmax[b * HH + t];
    __syncthreads();
    int bh = b * HH + w;
    float smax = smaxS[w];
#pragma unroll
    for (int r = 0; r < CRPB; ++r) {
        const float* ab = adjbuf[r];
        int i = i0 + r;
        float siv = si[(size_t)bh * NN + i];
        float m = siv + smax;
        m = (m >= 0.f) ? m : 0.2f * m;
        float z = 0.f;
        short* prow = PS + ((size_t)bh * NN + i) * KPAD;
#pragma unroll
        for (int k = 0; k < 4; ++k) {
            int jj = k * 64 + lane;
            bool valid = jj < KSEL;
            int j = valid ? idxS[w][jj] : 0;
            float av = ab[j];
            float e = siv + (valid ? sjS[w][jj] : 0.f);
            e = (e >= 0.f) ? e : 0.2f * e;
            float c = valid ? __expf(e - m) : 0.f;
            z += c;
            prow[jj] = f2bf(c * av);
        }
#pragma unroll
        for (int off = 32; off >= 1; off >>= 1) z += __shfl_xor(z, off);
        if (lane == 0) invZ[(size_t)bh * NN + i] = 1.0f / z;
    }
}

// ---------------------------------------------------------------------------
// K5: out = (P @ Whsel) * invZ via MFMA. No LDS; fragments from global.
__global__ __launch_bounds__(256) void pv_kernel(
        const short* __restrict__ PS, const short* __restrict__ Whsel,
        const float* __restrict__ invZ, float* __restrict__ out) {
    int bh = blockIdx.x >> 6, tile = blockIdx.x & 63;
    int b = bh >> 2, hh = bh & 3;
    int t = threadIdx.x, w = t >> 6, lane = t & 63;
    int mr = lane & 15, quad = lane >> 4;
    int mi = w >> 1, ni = w & 1;
    int i0 = tile * 32;
    const short* pA = PS + ((size_t)bh * NN + i0 + mi * 16 + mr) * KPAD + quad * 8;
    const short* pB = Whsel + ((size_t)bh * HD + ni * 16 + mr) * KPAD + quad * 8;
    float4v acc = {0.f, 0.f, 0.f, 0.f};
#pragma unroll
    for (int ks = 0; ks < 8; ++ks) {
        short8 afr = *(const short8*)(pA + ks * 32);
        short8 bfr = *(const short8*)(pB + ks * 32);
        acc = __builtin_amdgcn_mfma_f32_16x16x32_bf16(afr, bfr, acc, 0, 0, 0);
    }
#pragma unroll
    for (int r = 0; r < 4; ++r) {
        int i = i0 + mi * 16 + quad * 4 + r;
        int d = ni * 16 + mr;
        out[((size_t)(b * NN + i)) * (HH * HD) + hh * HD + d] =
            acc[r] * invZ[(size_t)bh * NN + i];
    }
}

// ---------------------------------------------------------------------------
extern "C" void kernel_launch(void* const* d_in, const int* in_sizes, int n_in,
                              void* d_out, int out_size, void* d_ws, size_t ws_size,
                              hipStream_t stream) {
    const float* h   = (const float*)d_in[0];   // [B,N,DIN]
    const float* adj = (const float*)d_in[1];   // [B,N,N]
    const float* W   = (const float*)d_in[2];   // [H,DIN,HD]
    const float* a   = (const float*)d_in[3];   // [H,2*HD]
    float* out = (float*)d_out;                 // [B,N,H*HD]

    float* si     = (float*)d_ws;                        // BH*NN f32
    float* sj     = si + (size_t)BH * NN;                // BH*NN
    float* invZ   = sj + (size_t)BH * NN;                // BH*NN
    float* sjsel  = invZ + (size_t)BH * NN;              // BH*KSEL
    float* sjmax  = sjsel + (size_t)BH * KSEL;           // BH (pad 16)
    int*   idxsel = (int*)(sjmax + 16);                  // BH*KSEL
    short* hbf    = (short*)(idxsel + (size_t)BH * KSEL);// BB*NN*DIN bf16
    short* Whg    = hbf + (size_t)BB * NN * DIN;         // BH*NN*HD bf16
    short* Whsel  = Whg + (size_t)BH * NN * HD;          // BH*HD*KPAD bf16
    short* PS     = Whsel + (size_t)BH * HD * KPAD;      // BH*NN*KPAD bf16

    hcvt_kernel<<<(BB * NN * DIN) / 1024, 256, 0, stream>>>(h, hbf);
    s_kernel<<<BH * 8, 256, 0, stream>>>(h, W, a, si, sj);
    wh_kernel<<<BH * 16, 256, 0, stream>>>(hbf, W, Whg);
    select_kernel<<<BH, 256, 0, stream>>>(sj, Whg, idxsel, sjsel, sjmax, Whsel);
    coef_kernel<<<BB * (NN / CRPB), 256, 0, stream>>>(adj, si, idxsel, sjsel, sjmax, PS, invZ);
    pv_kernel<<<BH * 64, 256, 0, stream>>>(PS, Whsel, invZ, out);
}

// Round 7
// 145.361 us; speedup vs baseline: 1.2186x; 1.1810x over previous
//
#include <hip/hip_runtime.h>
#include <hip/hip_bf16.h>
#include <cmath>

#define BB 4
#define NN 2048
#define DIN 128
#define HH 4
#define HD 32
#define KSEL 204            // int(0.1 * 2048)
#define BH (BB*HH)
#define KPAD 256            // K padded to 8 MFMA steps of 32
#define CRPB 4              // rows per coef block (all resident in LDS)

typedef __attribute__((ext_vector_type(8))) short short8;
typedef __attribute__((ext_vector_type(4))) short short4v;
typedef __attribute__((ext_vector_type(4))) float float4v;

static __device__ inline short f2bf(float x) {
    __hip_bfloat16 b = __float2bfloat16(x);   // RNE
    return __builtin_bit_cast(short, b);
}

// ---------------------------------------------------------------------------
// K0: h (f32) -> hbf (bf16), coalesced. 1M elems, 4 per thread.
__global__ __launch_bounds__(256) void hcvt_kernel(const float* __restrict__ h,
                                                   short* __restrict__ hbf) {
    int tid = blockIdx.x * 256 + threadIdx.x;
    float4 x = ((const float4*)h)[tid];
    short4v r;
    r[0] = f2bf(x.x); r[1] = f2bf(x.y); r[2] = f2bf(x.z); r[3] = f2bf(x.w);
    *(short4v*)(hbf + (size_t)tid * 4) = r;
}

// ---------------------------------------------------------------------------
// K1: s_i = h.(W@a1), s_j = h.(W@a2)  (all-f32 exact; feeds top-k).
__global__ __launch_bounds__(256) void s_kernel(const float* __restrict__ h,
                                                const float* __restrict__ W,
                                                const float* __restrict__ a,
                                                float* __restrict__ si, float* __restrict__ sj) {
    int bh = blockIdx.x >> 3, chunk = blockIdx.x & 7;
    int b = bh >> 2, hh = bh & 3;
    __shared__ float w1[128], w2[128];
    int t = threadIdx.x;
    {   // wa = W[hh] @ a-halves, computed in-block
        int f = t & 127, half = t >> 7;
        const float* Wp = W + (size_t)hh * (DIN * HD) + f * HD;
        const float* ap = a + hh * 64 + half * 32;
        float acc = 0.f;
#pragma unroll
        for (int d = 0; d < 32; ++d) acc += Wp[d] * ap[d];
        if (half == 0) w1[f] = acc; else w2[f] = acc;
    }
    __syncthreads();
    int n = chunk * 256 + t;
    const float4* hr = (const float4*)(h + ((size_t)b * NN + n) * DIN);
    float s1 = 0.f, s2 = 0.f;
#pragma unroll 8
    for (int q = 0; q < 32; ++q) {
        float4 x = hr[q];
        s1 += x.x * w1[q*4] + x.y * w1[q*4+1] + x.z * w1[q*4+2] + x.w * w1[q*4+3];
        s2 += x.x * w2[q*4] + x.y * w2[q*4+1] + x.z * w2[q*4+2] + x.w * w2[q*4+3];
    }
    int o = bh * NN + n;
    si[o] = s1; sj[o] = s2;
}

// ---------------------------------------------------------------------------
// K2: Whg[bh][n][d] (bf16) = hbf[b][n][:] @ W[h][:][d]  via MFMA 16x16x32 bf16
__global__ __launch_bounds__(256) void wh_kernel(const short* __restrict__ hbf,
                                                 const float* __restrict__ W,
                                                 short* __restrict__ Whg) {
    int bh = blockIdx.x >> 4, rtile = blockIdx.x & 15;
    int b = bh >> 2, hh = bh & 3;
    __shared__ short WT[32][136];   // WT[n][k] = bf16(W[hh][k][n])
    int t = threadIdx.x;
    for (int e = t; e < 32 * 128; e += 256) {
        int n = e >> 7, k = e & 127;
        WT[n][k] = f2bf(W[(size_t)hh * (DIN * HD) + k * HD + n]);
    }
    __syncthreads();
    int w = t >> 6, lane = t & 63, mr = lane & 15, quad = lane >> 4;
    int row_base = rtile * 128;
#pragma unroll
    for (int q = 0; q < 4; ++q) {
        int tt = w * 4 + q;
        int rt = tt >> 1, ct = tt & 1;
        int row0 = row_base + rt * 16;
        const short* hrow = hbf + ((size_t)b * NN + row0 + mr) * DIN + quad * 8;
        float4v acc = {0.f, 0.f, 0.f, 0.f};
#pragma unroll
        for (int ks = 0; ks < 4; ++ks) {
            short8 afr = *(const short8*)(hrow + ks * 32);
            short8 bfr = *(const short8*)&WT[ct * 16 + mr][ks * 32 + quad * 8];
            acc = __builtin_amdgcn_mfma_f32_16x16x32_bf16(afr, bfr, acc, 0, 0, 0);
        }
#pragma unroll
        for (int r = 0; r < 4; ++r) {
            int rowg = row0 + quad * 4 + r;
            Whg[((size_t)bh * NN + rowg) * HD + ct * 16 + mr] = f2bf(acc[r]);
        }
    }
}

// ---------------------------------------------------------------------------
// K3: radix-select top-KSEL per (b,h) + compaction + Whsel staging.
// 4-pass byte histogram on sortable keys; threshold bin found by PARALLEL
// block suffix-scan (was serial t==0 loop: 1024 dependent ds_reads = 48 us).
__global__ __launch_bounds__(256) void select_kernel(
        const float* __restrict__ sj, const short* __restrict__ Whg,
        int* __restrict__ idxsel, float* __restrict__ sjsel,
        float* __restrict__ sjmax, short* __restrict__ Whsel) {
    int bh = blockIdx.x;
    int t = threadIdx.x, lane = t & 63, w = t >> 6;
    __shared__ float sv[NN];
    __shared__ unsigned kv[NN];
    __shared__ int hist4[4][256];            // wave-privatized histograms
    __shared__ int binInfo[2];               // [0]=Bsel, [1]=cum_before
    __shared__ int wtot[4];
    __shared__ int wtotg[4], wtote[4], woffg[4], woffe[4];
    __shared__ float wmax[4];
    __shared__ int idxLDS[KSEL];

    const float* s = sj + (size_t)bh * NN;
    float lmax = -1e30f;
    for (int e = t; e < NN; e += 256) {
        float x = s[e];
        sv[e] = x;
        unsigned u = __builtin_bit_cast(unsigned, x);
        kv[e] = (u & 0x80000000u) ? ~u : (u | 0x80000000u);
        lmax = fmaxf(lmax, x);
    }
#pragma unroll
    for (int off = 32; off >= 1; off >>= 1) lmax = fmaxf(lmax, __shfl_xor(lmax, off));
    if (lane == 0) wmax[w] = lmax;
    __syncthreads();
    if (t == 0) sjmax[bh] = fmaxf(fmaxf(wmax[0], wmax[1]), fmaxf(wmax[2], wmax[3]));

    unsigned prefix = 0;
    int need = KSEL;
    for (int shift = 24; shift >= 0; shift -= 8) {
        hist4[0][t] = 0; hist4[1][t] = 0; hist4[2][t] = 0; hist4[3][t] = 0;
        __syncthreads();
        unsigned hmask = (shift < 24) ? (0xFFFFFFFFu << (shift + 8)) : 0u;
        for (int e = t; e < NN; e += 256) {
            unsigned k = kv[e];
            if (((k ^ prefix) & hmask) == 0)
                atomicAdd(&hist4[w][(k >> shift) & 255], 1);
        }
        __syncthreads();
        // thread t owns bin (255-t); hv = total count for that bin
        int bb = 255 - t;
        int hv = hist4[0][bb] + hist4[1][bb] + hist4[2][bb] + hist4[3][bb];
        // inclusive scan over t (descending-bin cumulative from the top)
        int sc = hv;
#pragma unroll
        for (int off = 1; off < 64; off <<= 1) {
            int u = __shfl_up(sc, off);
            if (lane >= off) sc += u;
        }
        if (lane == 63) wtot[w] = sc;
        __syncthreads();
        int woffset = 0;
#pragma unroll
        for (int i = 0; i < 4; ++i) woffset += (i < w) ? wtot[i] : 0;
        int incl = sc + woffset;
        int excl = incl - hv;
        if (incl >= need && excl < need) {   // unique thread
            binInfo[0] = bb;
            binInfo[1] = excl;
        }
        __syncthreads();
        prefix |= ((unsigned)binInfo[0]) << shift;
        need -= binInfo[1];
    }
    unsigned T = prefix;
    int n_gt = KSEL - need;        // count of keys strictly > T

    // ordered compaction: thread t owns indices [t*8, t*8+8)
    int j0 = t * 8;
    unsigned kk[8];
    int cg = 0, ce = 0;
#pragma unroll
    for (int r = 0; r < 8; ++r) {
        kk[r] = kv[j0 + r];
        cg += (kk[r] > T) ? 1 : 0;
        ce += (kk[r] == T) ? 1 : 0;
    }
    int sg = cg, se = ce;
#pragma unroll
    for (int off = 1; off < 64; off <<= 1) {
        int ug = __shfl_up(sg, off), ue = __shfl_up(se, off);
        if (lane >= off) { sg += ug; se += ue; }
    }
    if (lane == 63) { wtotg[w] = sg; wtote[w] = se; }
    __syncthreads();
    if (t == 0) {
        int rg = 0, re = 0;
        for (int i = 0; i < 4; ++i) {
            woffg[i] = rg; rg += wtotg[i];
            woffe[i] = re; re += wtote[i];
        }
    }
    __syncthreads();
    int pg = woffg[w] + sg - cg;   // exclusive prefix among key>T
    int te = woffe[w] + se - ce;   // exclusive prefix among key==T
#pragma unroll
    for (int r = 0; r < 8; ++r) {
        int j = j0 + r;
        if (kk[r] > T) {
            idxsel[bh * KSEL + pg] = j;
            sjsel[bh * KSEL + pg] = sv[j];
            idxLDS[pg] = j;
            pg++;
        } else if (kk[r] == T) {
            if (te < need) {
                int pos = n_gt + te;
                idxsel[bh * KSEL + pos] = j;
                sjsel[bh * KSEL + pos] = sv[j];
                idxLDS[pos] = j;
            }
            te++;
        }
    }
    __syncthreads();
    // Whsel[bh][d][jj]: B-operand layout, contiguous jj, zero K-tail
    for (int e = t; e < HD * KPAD; e += 256) {
        int d = e >> 8, jj = e & 255;
        short v = 0;
        if (jj < KSEL) v = Whg[((size_t)bh * NN + idxLDS[jj]) * HD + d];
        Whsel[((size_t)bh * HD + d) * KPAD + jj] = v;
    }
}

// ---------------------------------------------------------------------------
// K4: coefficients. Block = (b, CRPB rows, 4 heads-as-waves). All CRPB adj
// rows resident in LDS -> ONE barrier; each wave then runs free.
// PS = exp*adj (bf16, no 1/z); invZ written per (bh,row). ~39 KB LDS.
__global__ __launch_bounds__(256) void coef_kernel(
        const float* __restrict__ adj, const float* __restrict__ si,
        const int* __restrict__ idxsel, const float* __restrict__ sjsel,
        const float* __restrict__ sjmax, short* __restrict__ PS,
        float* __restrict__ invZ) {
    int b = blockIdx.x >> 9;          // 4
    int chunk = blockIdx.x & 511;     // 512 chunks of CRPB=4 rows
    __shared__ float adjbuf[CRPB][NN];
    __shared__ int   idxS[HH][KSEL];
    __shared__ float sjS[HH][KSEL];
    __shared__ float smaxS[HH];
    int t = threadIdx.x, w = t >> 6, lane = t & 63;
    int i0 = chunk * CRPB;
    const float* adjb = adj + (size_t)b * NN * NN;
    // stage all 4 rows (coalesced float4) + tables, one barrier
    {
        const float4* src = (const float4*)(adjb + (size_t)i0 * NN);
        float4* dst = (float4*)adjbuf;
#pragma unroll
        for (int q = 0; q < CRPB * 2; ++q)
            dst[q * 256 + t] = src[q * 256 + t];
    }
    for (int e = t; e < HH * KSEL; e += 256) {
        int hh = e / KSEL, jj = e - hh * KSEL;
        idxS[hh][jj] = idxsel[(b * HH + hh) * KSEL + jj];
        sjS[hh][jj]  = sjsel[(b * HH + hh) * KSEL + jj];
    }
    if (t < HH) smaxS[t] = sjmax[b * HH + t];
    __syncthreads();
    int bh = b * HH + w;
    float smax = smaxS[w];
#pragma unroll
    for (int r = 0; r < CRPB; ++r) {
        const float* ab = adjbuf[r];
        int i = i0 + r;
        float siv = si[(size_t)bh * NN + i];
        float m = siv + smax;
        m = (m >= 0.f) ? m : 0.2f * m;
        float z = 0.f;
        short* prow = PS + ((size_t)bh * NN + i) * KPAD;
#pragma unroll
        for (int k = 0; k < 4; ++k) {
            int jj = k * 64 + lane;
            bool valid = jj < KSEL;
            int j = valid ? idxS[w][jj] : 0;
            float av = ab[j];
            float e = siv + (valid ? sjS[w][jj] : 0.f);
            e = (e >= 0.f) ? e : 0.2f * e;
            float c = valid ? __expf(e - m) : 0.f;
            z += c;
            prow[jj] = f2bf(c * av);
        }
#pragma unroll
        for (int off = 32; off >= 1; off >>= 1) z += __shfl_xor(z, off);
        if (lane == 0) invZ[(size_t)bh * NN + i] = 1.0f / z;
    }
}

// ---------------------------------------------------------------------------
// K5: out = (P @ Whsel) * invZ via MFMA. No LDS; fragments from global.
__global__ __launch_bounds__(256) void pv_kernel(
        const short* __restrict__ PS, const short* __restrict__ Whsel,
        const float* __restrict__ invZ, float* __restrict__ out) {
    int bh = blockIdx.x >> 6, tile = blockIdx.x & 63;
    int b = bh >> 2, hh = bh & 3;
    int t = threadIdx.x, w = t >> 6, lane = t & 63;
    int mr = lane & 15, quad = lane >> 4;
    int mi = w >> 1, ni = w & 1;
    int i0 = tile * 32;
    const short* pA = PS + ((size_t)bh * NN + i0 + mi * 16 + mr) * KPAD + quad * 8;
    const short* pB = Whsel + ((size_t)bh * HD + ni * 16 + mr) * KPAD + quad * 8;
    float4v acc = {0.f, 0.f, 0.f, 0.f};
#pragma unroll
    for (int ks = 0; ks < 8; ++ks) {
        short8 afr = *(const short8*)(pA + ks * 32);
        short8 bfr = *(const short8*)(pB + ks * 32);
        acc = __builtin_amdgcn_mfma_f32_16x16x32_bf16(afr, bfr, acc, 0, 0, 0);
    }
#pragma unroll
    for (int r = 0; r < 4; ++r) {
        int i = i0 + mi * 16 + quad * 4 + r;
        int d = ni * 16 + mr;
        out[((size_t)(b * NN + i)) * (HH * HD) + hh * HD + d] =
            acc[r] * invZ[(size_t)bh * NN + i];
    }
}

// ---------------------------------------------------------------------------
extern "C" void kernel_launch(void* const* d_in, const int* in_sizes, int n_in,
                              void* d_out, int out_size, void* d_ws, size_t ws_size,
                              hipStream_t stream) {
    const float* h   = (const float*)d_in[0];   // [B,N,DIN]
    const float* adj = (const float*)d_in[1];   // [B,N,N]
    const float* W   = (const float*)d_in[2];   // [H,DIN,HD]
    const float* a   = (const float*)d_in[3];   // [H,2*HD]
    float* out = (float*)d_out;                 // [B,N,H*HD]

    float* si     = (float*)d_ws;                        // BH*NN f32
    float* sj     = si + (size_t)BH * NN;                // BH*NN
    float* invZ   = sj + (size_t)BH * NN;                // BH*NN
    float* sjsel  = invZ + (size_t)BH * NN;              // BH*KSEL
    float* sjmax  = sjsel + (size_t)BH * KSEL;           // BH (pad 16)
    int*   idxsel = (int*)(sjmax + 16);                  // BH*KSEL
    short* hbf    = (short*)(idxsel + (size_t)BH * KSEL);// BB*NN*DIN bf16
    short* Whg    = hbf + (size_t)BB * NN * DIN;         // BH*NN*HD bf16
    short* Whsel  = Whg + (size_t)BH * NN * HD;          // BH*HD*KPAD bf16
    short* PS     = Whsel + (size_t)BH * HD * KPAD;      // BH*NN*KPAD bf16

    hcvt_kernel<<<(BB * NN * DIN) / 1024, 256, 0, stream>>>(h, hbf);
    s_kernel<<<BH * 8, 256, 0, stream>>>(h, W, a, si, sj);
    wh_kernel<<<BH * 16, 256, 0, stream>>>(hbf, W, Whg);
    select_kernel<<<BH, 256, 0, stream>>>(sj, Whg, idxsel, sjsel, sjmax, Whsel);
    coef_kernel<<<BB * (NN / CRPB), 256, 0, stream>>>(adj, si, idxsel, sjsel, sjmax, PS, invZ);
    pv_kernel<<<BH * 64, 256, 0, stream>>>(PS, Whsel, invZ, out);
}

// Round 8
// 141.288 us; speedup vs baseline: 1.2538x; 1.0288x over previous
//
#include <hip/hip_runtime.h>
#include <hip/hip_bf16.h>
#include <cmath>

#define BB 4
#define NN 2048
#define DIN 128
#define HH 4
#define HD 32
#define KSEL 204            // int(0.1 * 2048)
#define BH (BB*HH)
#define KPAD 256            // K padded to 8 MFMA steps of 32
#define CRPB 4              // rows per coef block (all resident in LDS)

typedef __attribute__((ext_vector_type(8))) short short8;
typedef __attribute__((ext_vector_type(4))) short short4v;
typedef __attribute__((ext_vector_type(4))) float float4v;

static __device__ inline short f2bf(float x) {
    __hip_bfloat16 b = __float2bfloat16(x);   // RNE
    return __builtin_bit_cast(short, b);
}

// ---------------------------------------------------------------------------
// K1: fused balanced: every block converts 1/128 of h to bf16, then computes
// s_i = h.(W@a1), s_j = h.(W@a2) for its (bh, 256-row) slice. f32-exact.
__global__ __launch_bounds__(256) void hs_kernel(const float* __restrict__ h,
                                                 const float* __restrict__ W,
                                                 const float* __restrict__ a,
                                                 short* __restrict__ hbf,
                                                 float* __restrict__ si, float* __restrict__ sj) {
    int g = blockIdx.x;               // 0..127
    int bh = g >> 3, chunk = g & 7;
    int b = bh >> 2, hh = bh & 3;
    int t = threadIdx.x;
    {   // balanced convert: block g owns float4 range [g*2048, (g+1)*2048)
        const float4* src = (const float4*)h + (size_t)g * 2048;
        short4v* dst = (short4v*)hbf + (size_t)g * 2048;
#pragma unroll
        for (int q = 0; q < 8; ++q) {
            float4 x = src[q * 256 + t];
            short4v r;
            r[0] = f2bf(x.x); r[1] = f2bf(x.y); r[2] = f2bf(x.z); r[3] = f2bf(x.w);
            dst[q * 256 + t] = r;
        }
    }
    __shared__ float w1[128], w2[128];
    {   // wa = W[hh] @ a-halves, computed in-block
        int f = t & 127, half = t >> 7;
        const float* Wp = W + (size_t)hh * (DIN * HD) + f * HD;
        const float* ap = a + hh * 64 + half * 32;
        float acc = 0.f;
#pragma unroll
        for (int d = 0; d < 32; ++d) acc += Wp[d] * ap[d];
        if (half == 0) w1[f] = acc; else w2[f] = acc;
    }
    __syncthreads();
    int n = chunk * 256 + t;
    const float4* hr = (const float4*)(h + ((size_t)b * NN + n) * DIN);
    float s1 = 0.f, s2 = 0.f;
#pragma unroll 8
    for (int q = 0; q < 32; ++q) {
        float4 x = hr[q];
        s1 += x.x * w1[q*4] + x.y * w1[q*4+1] + x.z * w1[q*4+2] + x.w * w1[q*4+3];
        s2 += x.x * w2[q*4] + x.y * w2[q*4+1] + x.z * w2[q*4+2] + x.w * w2[q*4+3];
    }
    int o = bh * NN + n;
    si[o] = s1; sj[o] = s2;
}

// ---------------------------------------------------------------------------
// K2: Whg[bh][n][d] (bf16) = hbf[b][n][:] @ W[h][:][d]  via MFMA 16x16x32 bf16
__global__ __launch_bounds__(256) void wh_kernel(const short* __restrict__ hbf,
                                                 const float* __restrict__ W,
                                                 short* __restrict__ Whg) {
    int bh = blockIdx.x >> 4, rtile = blockIdx.x & 15;
    int b = bh >> 2, hh = bh & 3;
    __shared__ short WT[32][136];   // WT[n][k] = bf16(W[hh][k][n])
    int t = threadIdx.x;
    for (int e = t; e < 32 * 128; e += 256) {
        int n = e >> 7, k = e & 127;
        WT[n][k] = f2bf(W[(size_t)hh * (DIN * HD) + k * HD + n]);
    }
    __syncthreads();
    int w = t >> 6, lane = t & 63, mr = lane & 15, quad = lane >> 4;
    int row_base = rtile * 128;
#pragma unroll
    for (int q = 0; q < 4; ++q) {
        int tt = w * 4 + q;
        int rt = tt >> 1, ct = tt & 1;
        int row0 = row_base + rt * 16;
        const short* hrow = hbf + ((size_t)b * NN + row0 + mr) * DIN + quad * 8;
        float4v acc = {0.f, 0.f, 0.f, 0.f};
#pragma unroll
        for (int ks = 0; ks < 4; ++ks) {
            short8 afr = *(const short8*)(hrow + ks * 32);
            short8 bfr = *(const short8*)&WT[ct * 16 + mr][ks * 32 + quad * 8];
            acc = __builtin_amdgcn_mfma_f32_16x16x32_bf16(afr, bfr, acc, 0, 0, 0);
        }
#pragma unroll
        for (int r = 0; r < 4; ++r) {
            int rowg = row0 + quad * 4 + r;
            Whg[((size_t)bh * NN + rowg) * HD + ct * 16 + mr] = f2bf(acc[r]);
        }
    }
}

// ---------------------------------------------------------------------------
// K3: radix-select top-KSEL per (b,h), 1024 threads (16 waves). Keys in
// REGISTERS (2/thread): histogram passes do zero ds_reads; 16 wave-private
// histograms kill atomic contention. Then compaction + Whsel staging.
__global__ __launch_bounds__(1024) void select_kernel(
        const float* __restrict__ sj, const short* __restrict__ Whg,
        int* __restrict__ idxsel, float* __restrict__ sjsel,
        float* __restrict__ sjmax, short* __restrict__ Whsel) {
    int bh = blockIdx.x;
    int t = threadIdx.x, lane = t & 63, w = t >> 6;
    __shared__ float sv[NN];
    __shared__ int hist16[16][256];
    __shared__ int binInfo[2];               // [0]=Bsel, [1]=cum_before
    __shared__ int wtot[4];
    __shared__ int wtotg[16], wtote[16], woffg[16], woffe[16];
    __shared__ float wmax[16];
    __shared__ int idxLDS[KSEL];

    const float* s = sj + (size_t)bh * NN;
    int j0 = t * 2;
    float x0 = s[j0], x1 = s[j0 + 1];
    sv[j0] = x0; sv[j0 + 1] = x1;
    unsigned u0 = __builtin_bit_cast(unsigned, x0);
    unsigned u1 = __builtin_bit_cast(unsigned, x1);
    u0 = (u0 & 0x80000000u) ? ~u0 : (u0 | 0x80000000u);
    u1 = (u1 & 0x80000000u) ? ~u1 : (u1 | 0x80000000u);
    float lmax = fmaxf(x0, x1);
#pragma unroll
    for (int off = 32; off >= 1; off >>= 1) lmax = fmaxf(lmax, __shfl_xor(lmax, off));
    if (lane == 0) wmax[w] = lmax;
    __syncthreads();
    if (t == 0) {
        float m = wmax[0];
#pragma unroll
        for (int i = 1; i < 16; ++i) m = fmaxf(m, wmax[i]);
        sjmax[bh] = m;
    }

    unsigned prefix = 0;
    int need = KSEL;
#pragma unroll
    for (int shift = 24; shift >= 0; shift -= 8) {
        ((int*)hist16)[t] = 0; ((int*)hist16)[t + 1024] = 0;
        ((int*)hist16)[t + 2048] = 0; ((int*)hist16)[t + 3072] = 0;
        __syncthreads();
        unsigned hmask = (shift < 24) ? (0xFFFFFFFFu << (shift + 8)) : 0u;
        if (((u0 ^ prefix) & hmask) == 0) atomicAdd(&hist16[w][(u0 >> shift) & 255], 1);
        if (((u1 ^ prefix) & hmask) == 0) atomicAdd(&hist16[w][(u1 >> shift) & 255], 1);
        __syncthreads();
        int sc = 0, hv = 0, bb = 0;
        if (t < 256) {                 // waves 0..3, full waves
            bb = 255 - t;
            hv = 0;
#pragma unroll
            for (int i = 0; i < 16; ++i) hv += hist16[i][bb];
            sc = hv;
#pragma unroll
            for (int off = 1; off < 64; off <<= 1) {
                int u = __shfl_up(sc, off);
                if (lane >= off) sc += u;
            }
            if (lane == 63) wtot[w] = sc;
        }
        __syncthreads();
        if (t < 256) {
            int woffset = 0;
#pragma unroll
            for (int i = 0; i < 4; ++i) woffset += (i < w) ? wtot[i] : 0;
            int incl = sc + woffset;
            int excl = incl - hv;
            if (incl >= need && excl < need) {   // unique thread
                binInfo[0] = bb;
                binInfo[1] = excl;
            }
        }
        __syncthreads();
        prefix |= ((unsigned)binInfo[0]) << shift;
        need -= binInfo[1];
        __syncthreads();
    }
    unsigned T = prefix;
    int n_gt = KSEL - need;        // count of keys strictly > T

    // ordered compaction: thread t owns indices j0, j0+1
    int cg = (u0 > T ? 1 : 0) + (u1 > T ? 1 : 0);
    int ce = (u0 == T ? 1 : 0) + (u1 == T ? 1 : 0);
    int sg = cg, se = ce;
#pragma unroll
    for (int off = 1; off < 64; off <<= 1) {
        int ug = __shfl_up(sg, off), ue = __shfl_up(se, off);
        if (lane >= off) { sg += ug; se += ue; }
    }
    if (lane == 63) { wtotg[w] = sg; wtote[w] = se; }
    __syncthreads();
    if (t == 0) {
        int rg = 0, re = 0;
#pragma unroll
        for (int i = 0; i < 16; ++i) {
            woffg[i] = rg; rg += wtotg[i];
            woffe[i] = re; re += wtote[i];
        }
    }
    __syncthreads();
    int pg = woffg[w] + sg - cg;   // exclusive prefix among key>T
    int te = woffe[w] + se - ce;   // exclusive prefix among key==T
    {
        unsigned kk[2] = {u0, u1};
#pragma unroll
        for (int r = 0; r < 2; ++r) {
            int j = j0 + r;
            if (kk[r] > T) {
                idxsel[bh * KSEL + pg] = j;
                sjsel[bh * KSEL + pg] = sv[j];
                idxLDS[pg] = j;
                pg++;
            } else if (kk[r] == T) {
                if (te < need) {
                    int pos = n_gt + te;
                    idxsel[bh * KSEL + pos] = j;
                    sjsel[bh * KSEL + pos] = sv[j];
                    idxLDS[pos] = j;
                }
                te++;
            }
        }
    }
    __syncthreads();
    // Whsel[bh][d][jj]: B-operand layout, contiguous jj, zero K-tail
    for (int e = t; e < HD * KPAD; e += 1024) {
        int d = e >> 8, jj = e & 255;
        short v = 0;
        if (jj < KSEL) v = Whg[((size_t)bh * NN + idxLDS[jj]) * HD + d];
        Whsel[((size_t)bh * HD + d) * KPAD + jj] = v;
    }
}

// ---------------------------------------------------------------------------
// K4: coefficients. Block = (b, CRPB rows, 4 heads-as-waves). All CRPB adj
// rows resident in LDS -> ONE barrier. Tables padded to KPAD (sj=-1e30 ->
// exp underflows to exact 0): no predication. PS stored as short2.
__global__ __launch_bounds__(256) void coef_kernel(
        const float* __restrict__ adj, const float* __restrict__ si,
        const int* __restrict__ idxsel, const float* __restrict__ sjsel,
        const float* __restrict__ sjmax, short* __restrict__ PS,
        float* __restrict__ invZ) {
    int b = blockIdx.x >> 9;          // 4
    int chunk = blockIdx.x & 511;     // 512 chunks of CRPB=4 rows
    __shared__ float adjbuf[CRPB][NN];
    __shared__ int   idxS[HH][KPAD];
    __shared__ float sjS[HH][KPAD];
    __shared__ float smaxS[HH];
    int t = threadIdx.x, w = t >> 6, lane = t & 63;
    int i0 = chunk * CRPB;
    const float* adjb = adj + (size_t)b * NN * NN;
    // stage all 4 rows (coalesced float4) + padded tables, one barrier
    {
        const float4* src = (const float4*)(adjb + (size_t)i0 * NN);
        float4* dst = (float4*)adjbuf;
#pragma unroll
        for (int q = 0; q < CRPB * 2; ++q)
            dst[q * 256 + t] = src[q * 256 + t];
    }
    for (int e = t; e < HH * KPAD; e += 256) {
        int hh = e >> 8, jj = e & 255;
        bool v = jj < KSEL;
        idxS[hh][jj] = v ? idxsel[(b * HH + hh) * KSEL + jj] : 0;
        sjS[hh][jj]  = v ? sjsel[(b * HH + hh) * KSEL + jj] : -1e30f;
    }
    if (t < HH) smaxS[t] = sjmax[b * HH + t];
    __syncthreads();
    int bh = b * HH + w;
    float smax = smaxS[w];
#pragma unroll
    for (int r = 0; r < CRPB; ++r) {
        const float* ab = adjbuf[r];
        int i = i0 + r;
        float siv = si[(size_t)bh * NN + i];
        float m = siv + smax;
        m = (m >= 0.f) ? m : 0.2f * m;
        float z = 0.f;
        short* prow = PS + ((size_t)bh * NN + i) * KPAD;
#pragma unroll
        for (int k = 0; k < 2; ++k) {
            int jj = k * 128 + lane * 2;
            int ja = idxS[w][jj], jb = idxS[w][jj + 1];
            float ava = ab[ja], avb = ab[jb];
            float ea = siv + sjS[w][jj];
            float eb = siv + sjS[w][jj + 1];
            ea = (ea >= 0.f) ? ea : 0.2f * ea;
            eb = (eb >= 0.f) ? eb : 0.2f * eb;
            float ca = __expf(ea - m);
            float cb = __expf(eb - m);
            z += ca + cb;
            short2 p;
            p.x = f2bf(ca * ava);
            p.y = f2bf(cb * avb);
            *(short2*)&prow[jj] = p;
        }
#pragma unroll
        for (int off = 32; off >= 1; off >>= 1) z += __shfl_xor(z, off);
        if (lane == 0) invZ[(size_t)bh * NN + i] = 1.0f / z;
    }
}

// ---------------------------------------------------------------------------
// K5: out = (P @ Whsel) * invZ via MFMA. No LDS; fragments from global.
__global__ __launch_bounds__(256) void pv_kernel(
        const short* __restrict__ PS, const short* __restrict__ Whsel,
        const float* __restrict__ invZ, float* __restrict__ out) {
    int bh = blockIdx.x >> 6, tile = blockIdx.x & 63;
    int b = bh >> 2, hh = bh & 3;
    int t = threadIdx.x, w = t >> 6, lane = t & 63;
    int mr = lane & 15, quad = lane >> 4;
    int mi = w >> 1, ni = w & 1;
    int i0 = tile * 32;
    const short* pA = PS + ((size_t)bh * NN + i0 + mi * 16 + mr) * KPAD + quad * 8;
    const short* pB = Whsel + ((size_t)bh * HD + ni * 16 + mr) * KPAD + quad * 8;
    float4v acc = {0.f, 0.f, 0.f, 0.f};
#pragma unroll
    for (int ks = 0; ks < 8; ++ks) {
        short8 afr = *(const short8*)(pA + ks * 32);
        short8 bfr = *(const short8*)(pB + ks * 32);
        acc = __builtin_amdgcn_mfma_f32_16x16x32_bf16(afr, bfr, acc, 0, 0, 0);
    }
#pragma unroll
    for (int r = 0; r < 4; ++r) {
        int i = i0 + mi * 16 + quad * 4 + r;
        int d = ni * 16 + mr;
        out[((size_t)(b * NN + i)) * (HH * HD) + hh * HD + d] =
            acc[r] * invZ[(size_t)bh * NN + i];
    }
}

// ---------------------------------------------------------------------------
extern "C" void kernel_launch(void* const* d_in, const int* in_sizes, int n_in,
                              void* d_out, int out_size, void* d_ws, size_t ws_size,
                              hipStream_t stream) {
    const float* h   = (const float*)d_in[0];   // [B,N,DIN]
    const float* adj = (const float*)d_in[1];   // [B,N,N]
    const float* W   = (const float*)d_in[2];   // [H,DIN,HD]
    const float* a   = (const float*)d_in[3];   // [H,2*HD]
    float* out = (float*)d_out;                 // [B,N,H*HD]

    float* si     = (float*)d_ws;                        // BH*NN f32
    float* sj     = si + (size_t)BH * NN;                // BH*NN
    float* invZ   = sj + (size_t)BH * NN;                // BH*NN
    float* sjsel  = invZ + (size_t)BH * NN;              // BH*KSEL
    float* sjmax  = sjsel + (size_t)BH * KSEL;           // BH (pad 16)
    int*   idxsel = (int*)(sjmax + 16);                  // BH*KSEL
    short* hbf    = (short*)(idxsel + (size_t)BH * KSEL);// BB*NN*DIN bf16
    short* Whg    = hbf + (size_t)BB * NN * DIN;         // BH*NN*HD bf16
    short* Whsel  = Whg + (size_t)BH * NN * HD;          // BH*HD*KPAD bf16
    short* PS     = Whsel + (size_t)BH * HD * KPAD;      // BH*NN*KPAD bf16

    hs_kernel<<<BH * 8, 256, 0, stream>>>(h, W, a, hbf, si, sj);
    wh_kernel<<<BH * 16, 256, 0, stream>>>(hbf, W, Whg);
    select_kernel<<<BH, 1024, 0, stream>>>(sj, Whg, idxsel, sjsel, sjmax, Whsel);
    coef_kernel<<<BB * (NN / CRPB), 256, 0, stream>>>(adj, si, idxsel, sjsel, sjmax, PS, invZ);
    pv_kernel<<<BH * 64, 256, 0, stream>>>(PS, Whsel, invZ, out);
}

// Round 9
// 133.438 us; speedup vs baseline: 1.3275x; 1.0588x over previous
//
#include <hip/hip_runtime.h>
#include <hip/hip_bf16.h>
#include <cmath>

#define BB 4
#define NN 2048
#define DIN 128
#define HH 4
#define HD 32
#define KSEL 204            // int(0.1 * 2048)
#define BH (BB*HH)
#define KPAD 256            // K padded to 8 MFMA steps of 32
#define KST 264             // PSb row stride (shorts): 132 words -> 2-way banks (free)

typedef __attribute__((ext_vector_type(8))) short short8;
typedef __attribute__((ext_vector_type(4))) short short4v;
typedef __attribute__((ext_vector_type(4))) float float4v;

static __device__ inline short f2bf(float x) {
    __hip_bfloat16 b = __float2bfloat16(x);   // RNE
    return __builtin_bit_cast(short, b);
}

// ---------------------------------------------------------------------------
// K1: fused balanced: every block converts 1/128 of h to bf16, then computes
// s_i = h.(W@a1), s_j = h.(W@a2) for its (bh, 256-row) slice. f32-exact.
__global__ __launch_bounds__(256) void hs_kernel(const float* __restrict__ h,
                                                 const float* __restrict__ W,
                                                 const float* __restrict__ a,
                                                 short* __restrict__ hbf,
                                                 float* __restrict__ si, float* __restrict__ sj) {
    int g = blockIdx.x;               // 0..127
    int bh = g >> 3, chunk = g & 7;
    int b = bh >> 2, hh = bh & 3;
    int t = threadIdx.x;
    {   // balanced convert: block g owns float4 range [g*2048, (g+1)*2048)
        const float4* src = (const float4*)h + (size_t)g * 2048;
        short4v* dst = (short4v*)hbf + (size_t)g * 2048;
#pragma unroll
        for (int q = 0; q < 8; ++q) {
            float4 x = src[q * 256 + t];
            short4v r;
            r[0] = f2bf(x.x); r[1] = f2bf(x.y); r[2] = f2bf(x.z); r[3] = f2bf(x.w);
            dst[q * 256 + t] = r;
        }
    }
    __shared__ float w1[128], w2[128];
    {   // wa = W[hh] @ a-halves, computed in-block
        int f = t & 127, half = t >> 7;
        const float* Wp = W + (size_t)hh * (DIN * HD) + f * HD;
        const float* ap = a + hh * 64 + half * 32;
        float acc = 0.f;
#pragma unroll
        for (int d = 0; d < 32; ++d) acc += Wp[d] * ap[d];
        if (half == 0) w1[f] = acc; else w2[f] = acc;
    }
    __syncthreads();
    int n = chunk * 256 + t;
    const float4* hr = (const float4*)(h + ((size_t)b * NN + n) * DIN);
    float s1 = 0.f, s2 = 0.f;
#pragma unroll 8
    for (int q = 0; q < 32; ++q) {
        float4 x = hr[q];
        s1 += x.x * w1[q*4] + x.y * w1[q*4+1] + x.z * w1[q*4+2] + x.w * w1[q*4+3];
        s2 += x.x * w2[q*4] + x.y * w2[q*4+1] + x.z * w2[q*4+2] + x.w * w2[q*4+3];
    }
    int o = bh * NN + n;
    si[o] = s1; sj[o] = s2;
}

// ---------------------------------------------------------------------------
// K2: Whg[bh][n][d] (bf16) = hbf[b][n][:] @ W[h][:][d]  via MFMA 16x16x32 bf16
__global__ __launch_bounds__(256) void wh_kernel(const short* __restrict__ hbf,
                                                 const float* __restrict__ W,
                                                 short* __restrict__ Whg) {
    int bh = blockIdx.x >> 4, rtile = blockIdx.x & 15;
    int b = bh >> 2, hh = bh & 3;
    __shared__ short WT[32][136];   // WT[n][k] = bf16(W[hh][k][n])
    int t = threadIdx.x;
    for (int e = t; e < 32 * 128; e += 256) {
        int n = e >> 7, k = e & 127;
        WT[n][k] = f2bf(W[(size_t)hh * (DIN * HD) + k * HD + n]);
    }
    __syncthreads();
    int w = t >> 6, lane = t & 63, mr = lane & 15, quad = lane >> 4;
    int row_base = rtile * 128;
#pragma unroll
    for (int q = 0; q < 4; ++q) {
        int tt = w * 4 + q;
        int rt = tt >> 1, ct = tt & 1;
        int row0 = row_base + rt * 16;
        const short* hrow = hbf + ((size_t)b * NN + row0 + mr) * DIN + quad * 8;
        float4v acc = {0.f, 0.f, 0.f, 0.f};
#pragma unroll
        for (int ks = 0; ks < 4; ++ks) {
            short8 afr = *(const short8*)(hrow + ks * 32);
            short8 bfr = *(const short8*)&WT[ct * 16 + mr][ks * 32 + quad * 8];
            acc = __builtin_amdgcn_mfma_f32_16x16x32_bf16(afr, bfr, acc, 0, 0, 0);
        }
#pragma unroll
        for (int r = 0; r < 4; ++r) {
            int rowg = row0 + quad * 4 + r;
            Whg[((size_t)bh * NN + rowg) * HD + ct * 16 + mr] = f2bf(acc[r]);
        }
    }
}

// ---------------------------------------------------------------------------
// K3: radix-select top-KSEL per (b,h), 1024 threads (16 waves). Keys in
// REGISTERS (2/thread); 16 wave-private histograms. Compaction + Whsel staging.
__global__ __launch_bounds__(1024) void select_kernel(
        const float* __restrict__ sj, const short* __restrict__ Whg,
        int* __restrict__ idxsel, float* __restrict__ sjsel,
        float* __restrict__ sjmax, short* __restrict__ Whsel) {
    int bh = blockIdx.x;
    int t = threadIdx.x, lane = t & 63, w = t >> 6;
    __shared__ float sv[NN];
    __shared__ int hist16[16][256];
    __shared__ int binInfo[2];               // [0]=Bsel, [1]=cum_before
    __shared__ int wtot[4];
    __shared__ int wtotg[16], wtote[16], woffg[16], woffe[16];
    __shared__ float wmax[16];
    __shared__ int idxLDS[KSEL];

    const float* s = sj + (size_t)bh * NN;
    int j0 = t * 2;
    float x0 = s[j0], x1 = s[j0 + 1];
    sv[j0] = x0; sv[j0 + 1] = x1;
    unsigned u0 = __builtin_bit_cast(unsigned, x0);
    unsigned u1 = __builtin_bit_cast(unsigned, x1);
    u0 = (u0 & 0x80000000u) ? ~u0 : (u0 | 0x80000000u);
    u1 = (u1 & 0x80000000u) ? ~u1 : (u1 | 0x80000000u);
    float lmax = fmaxf(x0, x1);
#pragma unroll
    for (int off = 32; off >= 1; off >>= 1) lmax = fmaxf(lmax, __shfl_xor(lmax, off));
    if (lane == 0) wmax[w] = lmax;
    __syncthreads();
    if (t == 0) {
        float m = wmax[0];
#pragma unroll
        for (int i = 1; i < 16; ++i) m = fmaxf(m, wmax[i]);
        sjmax[bh] = m;
    }

    unsigned prefix = 0;
    int need = KSEL;
#pragma unroll
    for (int shift = 24; shift >= 0; shift -= 8) {
        ((int*)hist16)[t] = 0; ((int*)hist16)[t + 1024] = 0;
        ((int*)hist16)[t + 2048] = 0; ((int*)hist16)[t + 3072] = 0;
        __syncthreads();
        unsigned hmask = (shift < 24) ? (0xFFFFFFFFu << (shift + 8)) : 0u;
        if (((u0 ^ prefix) & hmask) == 0) atomicAdd(&hist16[w][(u0 >> shift) & 255], 1);
        if (((u1 ^ prefix) & hmask) == 0) atomicAdd(&hist16[w][(u1 >> shift) & 255], 1);
        __syncthreads();
        int sc = 0, hv = 0, bb = 0;
        if (t < 256) {                 // waves 0..3
            bb = 255 - t;
            hv = 0;
#pragma unroll
            for (int i = 0; i < 16; ++i) hv += hist16[i][bb];
            sc = hv;
#pragma unroll
            for (int off = 1; off < 64; off <<= 1) {
                int u = __shfl_up(sc, off);
                if (lane >= off) sc += u;
            }
            if (lane == 63) wtot[w] = sc;
        }
        __syncthreads();
        if (t < 256) {
            int woffset = 0;
#pragma unroll
            for (int i = 0; i < 4; ++i) woffset += (i < w) ? wtot[i] : 0;
            int incl = sc + woffset;
            int excl = incl - hv;
            if (incl >= need && excl < need) {   // unique thread
                binInfo[0] = bb;
                binInfo[1] = excl;
            }
        }
        __syncthreads();
        prefix |= ((unsigned)binInfo[0]) << shift;
        need -= binInfo[1];
        __syncthreads();
    }
    unsigned T = prefix;
    int n_gt = KSEL - need;        // count of keys strictly > T

    // ordered compaction: thread t owns indices j0, j0+1
    int cg = (u0 > T ? 1 : 0) + (u1 > T ? 1 : 0);
    int ce = (u0 == T ? 1 : 0) + (u1 == T ? 1 : 0);
    int sg = cg, se = ce;
#pragma unroll
    for (int off = 1; off < 64; off <<= 1) {
        int ug = __shfl_up(sg, off), ue = __shfl_up(se, off);
        if (lane >= off) { sg += ug; se += ue; }
    }
    if (lane == 63) { wtotg[w] = sg; wtote[w] = se; }
    __syncthreads();
    if (t == 0) {
        int rg = 0, re = 0;
#pragma unroll
        for (int i = 0; i < 16; ++i) {
            woffg[i] = rg; rg += wtotg[i];
            woffe[i] = re; re += wtote[i];
        }
    }
    __syncthreads();
    int pg = woffg[w] + sg - cg;   // exclusive prefix among key>T
    int te = woffe[w] + se - ce;   // exclusive prefix among key==T
    {
        unsigned kk[2] = {u0, u1};
#pragma unroll
        for (int r = 0; r < 2; ++r) {
            int j = j0 + r;
            if (kk[r] > T) {
                idxsel[bh * KSEL + pg] = j;
                sjsel[bh * KSEL + pg] = sv[j];
                idxLDS[pg] = j;
                pg++;
            } else if (kk[r] == T) {
                if (te < need) {
                    int pos = n_gt + te;
                    idxsel[bh * KSEL + pos] = j;
                    sjsel[bh * KSEL + pos] = sv[j];
                    idxLDS[pos] = j;
                }
                te++;
            }
        }
    }
    __syncthreads();
    // Whsel[bh][d][jj]: B-operand layout, contiguous jj, zero K-tail
    for (int e = t; e < HD * KPAD; e += 1024) {
        int d = e >> 8, jj = e & 255;
        short v = 0;
        if (jj < KSEL) v = Whg[((size_t)bh * NN + idxLDS[jj]) * HD + d];
        Whsel[((size_t)bh * HD + d) * KPAD + jj] = v;
    }
}

// ---------------------------------------------------------------------------
// K4: FUSED attention. Block = (b, 16 rows, 4 heads-as-waves), grid 512.
// 4 stages: 4 dense adj rows -> LDS (shared by all heads); wave w computes
// head w's P rows into its PRIVATE PSb[w] (bf16, stride 264); barriers only
// guard adjbuf. Then wave w MFMAs PSb[w] @ bfr (registers) -> out * invZ.
// LDS ~75 KB -> 2 blocks/CU; no PS global round-trip.
__global__ __launch_bounds__(256) void attn2_kernel(
        const float* __restrict__ adj, const float* __restrict__ si,
        const int* __restrict__ idxsel, const float* __restrict__ sjsel,
        const float* __restrict__ sjmax, const short* __restrict__ Whsel,
        float* __restrict__ out) {
    int b = blockIdx.x >> 7;        // 4
    int tile = blockIdx.x & 127;    // 128 tiles of 16 rows
    __shared__ float adjbuf[4][NN];          // 32 KB
    __shared__ short PSb[HH][16][KST];       // 33 KB, per-head private
    __shared__ int   idxS[HH][KPAD];         // 4 KB
    __shared__ float sjS[HH][KPAD];          // 4 KB
    __shared__ float invZS[HH][16];
    __shared__ float smaxS[HH];
    int t = threadIdx.x, w = t >> 6, lane = t & 63;
    int mr = lane & 15, quad = lane >> 4;

    // padded per-head tables
    for (int e = t; e < HH * KPAD; e += 256) {
        int hh = e >> 8, jj = e & 255;
        bool v = jj < KSEL;
        idxS[hh][jj] = v ? idxsel[(b * HH + hh) * KSEL + jj] : 0;
        sjS[hh][jj]  = v ? sjsel[(b * HH + hh) * KSEL + jj] : -1e30f;
    }
    if (t < HH) smaxS[t] = sjmax[b * HH + t];

    // B-fragments for head w (registers, reused all block)
    short8 bfr[2][8];
    {
        const short* wp = Whsel + (size_t)((b * HH + w) * HD) * KPAD;
#pragma unroll
        for (int ni = 0; ni < 2; ++ni)
#pragma unroll
            for (int ks = 0; ks < 8; ++ks)
                bfr[ni][ks] = *(const short8*)(wp + (size_t)(ni * 16 + mr) * KPAD + ks * 32 + quad * 8);
    }

    int i0 = tile * 16;
    const float* adjb = adj + (size_t)b * NN * NN;
    // stage 0: 4 dense adj rows
    {
        const float4* src = (const float4*)(adjb + (size_t)i0 * NN);
        float4* dst = (float4*)adjbuf;
#pragma unroll
        for (int q = 0; q < 8; ++q)
            dst[q * 256 + t] = src[q * 256 + t];
    }
    __syncthreads();

    int bh = b * HH + w;
    float smax = smaxS[w];
    for (int s = 0; s < 4; ++s) {
#pragma unroll
        for (int r = 0; r < 4; ++r) {
            int i_loc = s * 4 + r;
            int i = i0 + i_loc;
            float siv = si[(size_t)bh * NN + i];
            float m = siv + smax;
            m = (m >= 0.f) ? m : 0.2f * m;
            float z = 0.f;
            short* prow = &PSb[w][i_loc][0];
#pragma unroll
            for (int k = 0; k < 2; ++k) {
                int jj = k * 128 + lane * 2;
                int ja = idxS[w][jj], jb = idxS[w][jj + 1];
                float ava = adjbuf[r][ja], avb = adjbuf[r][jb];
                float ea = siv + sjS[w][jj];
                float eb = siv + sjS[w][jj + 1];
                ea = (ea >= 0.f) ? ea : 0.2f * ea;
                eb = (eb >= 0.f) ? eb : 0.2f * eb;
                float ca = __expf(ea - m);
                float cb = __expf(eb - m);
                z += ca + cb;
                short2 p;
                p.x = f2bf(ca * ava);
                p.y = f2bf(cb * avb);
                *(short2*)&prow[jj] = p;
            }
#pragma unroll
            for (int off = 32; off >= 1; off >>= 1) z += __shfl_xor(z, off);
            if (lane == 0) invZS[w][i_loc] = 1.0f / z;
        }
        if (s < 3) {
            __syncthreads();   // all waves done reading adjbuf
            const float4* src = (const float4*)(adjb + (size_t)(i0 + (s + 1) * 4) * NN);
            float4* dst = (float4*)adjbuf;
#pragma unroll
            for (int q = 0; q < 8; ++q)
                dst[q * 256 + t] = src[q * 256 + t];
            __syncthreads();
        }
    }
    // MFMA phase: PSb[w] is wave-private -> no barrier needed.
#pragma unroll
    for (int ni = 0; ni < 2; ++ni) {
        float4v acc = {0.f, 0.f, 0.f, 0.f};
#pragma unroll
        for (int ks = 0; ks < 8; ++ks) {
            short8 afr = *(const short8*)&PSb[w][mr][ks * 32 + quad * 8];
            acc = __builtin_amdgcn_mfma_f32_16x16x32_bf16(afr, bfr[ni][ks], acc, 0, 0, 0);
        }
#pragma unroll
        for (int r = 0; r < 4; ++r) {
            int i_loc = quad * 4 + r;
            int d = ni * 16 + mr;
            out[((size_t)(b * NN + i0 + i_loc)) * (HH * HD) + w * HD + d] =
                acc[r] * invZS[w][i_loc];
        }
    }
}

// ---------------------------------------------------------------------------
extern "C" void kernel_launch(void* const* d_in, const int* in_sizes, int n_in,
                              void* d_out, int out_size, void* d_ws, size_t ws_size,
                              hipStream_t stream) {
    const float* h   = (const float*)d_in[0];   // [B,N,DIN]
    const float* adj = (const float*)d_in[1];   // [B,N,N]
    const float* W   = (const float*)d_in[2];   // [H,DIN,HD]
    const float* a   = (const float*)d_in[3];   // [H,2*HD]
    float* out = (float*)d_out;                 // [B,N,H*HD]

    float* si     = (float*)d_ws;                        // BH*NN f32
    float* sj     = si + (size_t)BH * NN;                // BH*NN
    float* sjsel  = sj + (size_t)BH * NN;                // BH*KSEL
    float* sjmax  = sjsel + (size_t)BH * KSEL;           // BH (pad 16)
    int*   idxsel = (int*)(sjmax + 16);                  // BH*KSEL
    short* hbf    = (short*)(idxsel + (size_t)BH * KSEL);// BB*NN*DIN bf16
    short* Whg    = hbf + (size_t)BB * NN * DIN;         // BH*NN*HD bf16
    short* Whsel  = Whg + (size_t)BH * NN * HD;          // BH*HD*KPAD bf16

    hs_kernel<<<BH * 8, 256, 0, stream>>>(h, W, a, hbf, si, sj);
    wh_kernel<<<BH * 16, 256, 0, stream>>>(hbf, W, Whg);
    select_kernel<<<BH, 1024, 0, stream>>>(sj, Whg, idxsel, sjsel, sjmax, Whsel);
    attn2_kernel<<<BB * 128, 256, 0, stream>>>(adj, si, idxsel, sjsel, sjmax, Whsel, out);
}